// Round 1
// baseline (239.155 us; speedup 1.0000x reference)
//
#include <hip/hip_runtime.h>
#include <math.h>

// Problem: (256, 4096, 33) f32. Row = [K, w1[0..31]]. K passes through.
// 4 iterations of: scan push-apart (31 steps) + clip to [min_d, pi-min_d].
// Rows independent -> 1 thread per row, row in registers.
// 33-float rows are uncoalescable directly -> stage 256-row tile in LDS with
// coalesced float4 global loads/stores. LDS row stride 33 -> 2-way bank
// aliasing across wave64 (free on gfx950).

#define ROWS_PER_BLOCK 256
#define ROW 33
#define FPB (ROWS_PER_BLOCK * ROW)   // 8448 floats per block tile
#define V4PB (FPB / 4)               // 2112 float4 per tile

__global__ __launch_bounds__(256) void lsp_stability_kernel(
    const float* __restrict__ in, float* __restrict__ out)
{
    __shared__ float smem[FPB];
    const int tid = threadIdx.x;
    const long long base = (long long)blockIdx.x * FPB;

    const float4* __restrict__ in4 = (const float4*)(in + base);
    float4* __restrict__ out4 = (float4*)(out + base);
    float4* s4 = (float4*)smem;

    // Coalesced global -> LDS staging (2112 float4: 8 full rounds + 64 tail)
#pragma unroll
    for (int j = 0; j < 8; ++j)
        s4[tid + j * 256] = in4[tid + j * 256];
    if (tid < (V4PB - 2048))
        s4[2048 + tid] = in4[2048 + tid];
    __syncthreads();

    const float MIND = (float)(0.01 * M_PI / 33.0);  // RATE*pi/(ORDER+1), f64 then f32 like np
    const float PI_F = (float)M_PI;
    const float HI = PI_F - MIND;                    // f32 subtraction, matches jnp

    // Each thread owns one row; w1 (32 elems) lives in registers.
    float w[32];
    float* row = smem + tid * ROW;
#pragma unroll
    for (int k = 0; k < 32; ++k) w[k] = row[k + 1];

#pragma unroll
    for (int it = 0; it < 4; ++it) {
        // scan: c starts at w[0]; step k: s=0.5*max(min_d-(w[k]-c),0);
        //   out[k-1]=c-s; c=w[k]+s.  Final: out[31]=c.
        float c = w[0];
#pragma unroll
        for (int k = 1; k < 32; ++k) {
            float nxt = w[k];
            float sft = 0.5f * fmaxf(MIND - (nxt - c), 0.0f);
            w[k - 1] = c - sft;
            c = nxt + sft;
        }
        w[31] = c;
        // clip
#pragma unroll
        for (int k = 0; k < 32; ++k)
            w[k] = fminf(fmaxf(w[k], MIND), HI);
    }

    // Row element 0 (K) is already in LDS untouched; write back w1 only.
#pragma unroll
    for (int k = 0; k < 32; ++k) row[k + 1] = w[k];
    __syncthreads();

    // Coalesced LDS -> global
#pragma unroll
    for (int j = 0; j < 8; ++j)
        out4[tid + j * 256] = s4[tid + j * 256];
    if (tid < (V4PB - 2048))
        out4[2048 + tid] = s4[2048 + tid];
}

extern "C" void kernel_launch(void* const* d_in, const int* in_sizes, int n_in,
                              void* d_out, int out_size, void* d_ws, size_t ws_size,
                              hipStream_t stream) {
    const float* in = (const float*)d_in[0];
    float* out = (float*)d_out;
    // total = 256*4096*33 = 34,603,008 floats; 8448 per block -> 4096 blocks exactly.
    const int blocks = in_sizes[0] / FPB;
    lsp_stability_kernel<<<blocks, ROWS_PER_BLOCK, 0, stream>>>(in, out);
}

// Round 2
// 237.142 us; speedup vs baseline: 1.0085x; 1.0085x over previous
//
#include <hip/hip_runtime.h>
#include <math.h>

// (256, 4096, 33) f32 rows: [K, w1[0..31]]; K passes through; w1 gets
// 4x (31-step push-apart scan + clip). One thread per row, row in registers.
//
// R1 post-mortem: 256-thr/33KB-LDS blocks -> only 4 blocks/CU, bulk-sync
// phases convoy -> 2.47 TB/s, 84 us (latency-bound, not roofline).
// R2: 128-thr blocks (16.9 KB LDS -> 9 blocks/CU, 18 waves/CU) so resident
// blocks stagger load/compute/store phases; staging via
// __builtin_amdgcn_global_load_lds width=16 (lane mapping is exactly the
// wave-uniform-base + lane*16 contiguous pattern) to drop the VGPR
// round-trip and all ds_write staging instructions.

#define ROWS 128
#define THREADS 128
#define ROW 33
#define FPB (ROWS * ROW)      // 4224 floats per block tile
#define V4PB (FPB / 4)        // 1056 float4 per tile

typedef const __attribute__((address_space(1))) unsigned int* gas_p;
typedef __attribute__((address_space(3))) unsigned int* las_p;

__global__ __launch_bounds__(THREADS) void lsp_stability_kernel(
    const float* __restrict__ in, float* __restrict__ out)
{
    __shared__ alignas(16) float smem[FPB];
    const int tid = threadIdx.x;
    const long long base = (long long)blockIdx.x * FPB;

    const float* gin = in + base;
    float4* out4 = (float4*)(out + base);
    float4* s4 = (float4*)smem;

    // Global -> LDS direct DMA, 16 B per lane per round. 1056 float4:
    // 8 full rounds of 128 + 32-thread tail. Lane l of wave w targets LDS
    // offset (j*128 + w*64 + l)*16 = wave-uniform base + l*16 (contiguous).
    gas_p g = (gas_p)gin;
    las_p s = (las_p)smem;
#pragma unroll
    for (int j = 0; j < 8; ++j)
        __builtin_amdgcn_global_load_lds(g + (size_t)(tid + j * THREADS) * 4,
                                         s + (size_t)(tid + j * THREADS) * 4,
                                         16, 0, 0);
    if (tid < (V4PB - 8 * THREADS))
        __builtin_amdgcn_global_load_lds(g + (size_t)(tid + 8 * THREADS) * 4,
                                         s + (size_t)(tid + 8 * THREADS) * 4,
                                         16, 0, 0);
    __syncthreads();   // drains vmcnt before barrier -> LDS valid

    const float MIND = (float)(0.01 * M_PI / 33.0);  // RATE*pi/(ORDER+1)
    const float PI_F = (float)M_PI;
    const float HI = PI_F - MIND;

    // Each thread owns one row; w1 (32 elems) in registers.
    // LDS row stride 33 -> 2-way bank aliasing across wave64 (free, m136).
    float w[32];
    float* row = smem + tid * ROW;
#pragma unroll
    for (int k = 0; k < 32; ++k) w[k] = row[k + 1];

#pragma unroll
    for (int it = 0; it < 4; ++it) {
        float c = w[0];
#pragma unroll
        for (int k = 1; k < 32; ++k) {
            float nxt = w[k];
            float sft = 0.5f * fmaxf(MIND - (nxt - c), 0.0f);
            w[k - 1] = c - sft;   // 0.5*m is exact (pow2 mul) -> fma-safe
            c = nxt + sft;
        }
        w[31] = c;
#pragma unroll
        for (int k = 0; k < 32; ++k)
            w[k] = fminf(fmaxf(w[k], MIND), HI);
    }

    // K (element 0) still in LDS untouched; write back w1 only.
#pragma unroll
    for (int k = 0; k < 32; ++k) row[k + 1] = w[k];
    __syncthreads();

    // Coalesced LDS -> global store.
#pragma unroll
    for (int j = 0; j < 8; ++j)
        out4[tid + j * THREADS] = s4[tid + j * THREADS];
    if (tid < (V4PB - 8 * THREADS))
        out4[tid + 8 * THREADS] = s4[tid + 8 * THREADS];
}

extern "C" void kernel_launch(void* const* d_in, const int* in_sizes, int n_in,
                              void* d_out, int out_size, void* d_ws, size_t ws_size,
                              hipStream_t stream) {
    const float* in = (const float*)d_in[0];
    float* out = (float*)d_out;
    // total = 256*4096*33 = 34,603,008 floats; 4224 per block -> 8192 blocks.
    const int blocks = in_sizes[0] / FPB;
    lsp_stability_kernel<<<blocks, THREADS, 0, stream>>>(in, out);
}